// Round 13
// baseline (238.592 us; speedup 1.0000x reference)
//
#include <hip/hip_runtime.h>

#define NCH 12
#define NB  4
#define BC  48
#define HW0 (512 * 512)

// Gaussian 1-D weights (win=11, sigma=1.5), exact to f32 — computed offline.
#define GK_INIT { 0.00102840f, 0.00759863f, 0.03600078f, 0.10936081f, \
                  0.21300541f, 0.26601164f, 0.21300541f, 0.10936081f, \
                  0.03600078f, 0.00759863f, 0.00102840f }

// ---------------------------------------------------------------------------
// Prep (single-pass, validated R11 form): one thread per 2x2 patch.
// UT = {u bf16 (hi16) | one-hot mask (lo16)}; XY1 = {y count<<16 | x bf16}.
__global__ __launch_bounds__(256)
void k_prep(const float* __restrict__ pred, const int* __restrict__ tgt,
            unsigned* __restrict__ UT, unsigned* __restrict__ XY1,
            double* __restrict__ acc) {
    if (blockIdx.x == 0) {
        for (int t = threadIdx.x; t < 480; t += 256) acc[t] = 0.0;
    }
    const int blk = blockIdx.x;          // 0..1023
    const int b  = blk >> 8;             // batch
    const int py = blk & 255;            // patch row
    const int px = threadIdx.x;          // patch col
    const size_t o00 = (size_t)(2 * py) * 512 + 2 * px;
    const size_t o10 = o00 + 512;
    const float* Pb = pred + (size_t)b * NCH * HW0;

    float ex[NCH], ey[NCH], ez[NCH], ew[NCH];
    float s00 = 0.f, s01 = 0.f, s10 = 0.f, s11 = 0.f;
#pragma unroll
    for (int c = 0; c < NCH; ++c) {
        const float* pc = Pb + (size_t)c * HW0;
        float2 r0 = *(const float2*)(pc + o00);
        float2 r1 = *(const float2*)(pc + o10);
        ex[c] = __expf(r0.x); ey[c] = __expf(r0.y);
        ez[c] = __expf(r1.x); ew[c] = __expf(r1.y);
        s00 += ex[c]; s01 += ey[c]; s10 += ez[c]; s11 += ew[c];
    }
    float u00 = 1.f / s00, u01 = 1.f / s01, u10 = 1.f / s10, u11 = 1.f / s11;

    const int* Tb = tgt + (size_t)b * HW0;
    int2 t0 = *(const int2*)(Tb + o00);
    int2 t1 = *(const int2*)(Tb + o10);

    unsigned* UTb = UT + (size_t)b * HW0;
    {
        unsigned w00 = (((__float_as_uint(u00) + 0x8000u) >> 16) << 16) | (1u << t0.x);
        unsigned w01 = (((__float_as_uint(u01) + 0x8000u) >> 16) << 16) | (1u << t0.y);
        unsigned w10 = (((__float_as_uint(u10) + 0x8000u) >> 16) << 16) | (1u << t1.x);
        unsigned w11 = (((__float_as_uint(u11) + 0x8000u) >> 16) << 16) | (1u << t1.y);
        *(uint2*)(UTb + o00) = make_uint2(w00, w01);
        *(uint2*)(UTb + o10) = make_uint2(w10, w11);
    }

#pragma unroll
    for (int c = 0; c < NCH; ++c) {
        float xs = 0.25f * (ex[c] * u00 + ey[c] * u01 + ez[c] * u10 + ew[c] * u11);
        unsigned xb = (__float_as_uint(xs) + 0x8000u) >> 16;   // bf16 rn
        unsigned cnt = (unsigned)(t0.x == c) + (unsigned)(t0.y == c)
                     + (unsigned)(t1.x == c) + (unsigned)(t1.y == c);
        size_t oidx = ((size_t)(b * NCH + c) * 256 + py) * 256 + px;
        XY1[oidx] = ((cnt << 6) << 16) | xb;                   // {y*256 | x bf16}
    }
}

// ---------------------------------------------------------------------------
// LDS: s0 branch uses the ORIGINAL non-overlapped 19.3 KB layout (ran
// 8 blocks/CU at baseline). Rest branch aliases ONLY tm5 (2.9 KB) onto the
// dead sxy halo; tm4 is non-aliased and stored with no extra live range —
// only ac4[6] crosses the extra barrier (spill-proof, unlike R12).
// Union = 19.3 KB -> 8 blocks/CU for both branches.
union SMem {
    struct {
        float sx[42 * 43 + 4];                  // 7240 B
        uint2 tm4[42 * 35];                     // 11760 B
        unsigned long long ybits[30];           // 240 B
        float red[8];                           // 32 B   => 19272 B
    } s0;
    struct {
        union {
            unsigned int sxy[42 * 43 + 4];      // halo (dead after hconv)
            unsigned short tm5[42 * 35];        // yy moment (written after)
        } ovl;                                  // 7240 B
        uint2 tm4[42 * 35];                     // 11760 B
        float red[8];                           // 32 B   => 19032 B
    } rg;
};

// ---------------------------------------------------------------------------
// Scale-0 SSIM tile — VERBATIM R11 body (2 barriers, no aliasing).
__device__ __forceinline__ void ssim0_tile(
    const float* __restrict__ pred, const unsigned* __restrict__ UT,
    double* __restrict__ acc, int tile, int bc,
    float* sx, uint2* tm4, unsigned long long* ybits, float* red) {
    constexpr int SS = 43;
    constexpr int TS = 35;
    constexpr int H = 512, W = 512, OH = 502, OW = 502, tilesX = 16;
    const float gk[11] = GK_INIT;

    const int ty = tile / tilesX, tx = tile - ty * tilesX;
    const int oy = ty * 32, ox = tx * 32;
    const int tid = threadIdx.x;
    const bool interior = (oy + 41 < H) && (ox + 41 < W);

    const int b = bc / NCH, cls = bc - (bc / NCH) * NCH;
    const float* Pb = pred + (((size_t)b * NCH + cls) << 18);
    const unsigned* Ub = UT + ((size_t)b << 18);

    // ---- halo 42x42, phase A: issue all loads (no cross-lane ops)
    float pv[7];
    unsigned uw[7];
    {
        int r = tid / 42, c = tid - (tid / 42) * 42;
#pragma unroll
        for (int k = 0; k < 7; ++k) {
            bool inr = (k < 6) || (tid < 228);
            int gy = oy + r, gx = ox + c;
            bool ld = inr && (interior || (gy < H && gx < W));
            pv[k] = 0.f; uw[k] = 0u;
            if (ld) {
                int off = gy * W + gx;
                pv[k] = Pb[off];
                uw[k] = Ub[off];
            }
            c += 4; r += 6;
            if (c >= 42) { c -= 42; r += 1; }
        }
    }
    // ---- halo phase B: exp + ballot + LDS store
    {
        int r = tid / 42, c = tid - (tid / 42) * 42;
#pragma unroll
        for (int k = 0; k < 7; ++k) {
            bool inr = (k < 6) || (tid < 228);
            float uf = __uint_as_float(uw[k] & 0xFFFF0000u);
            float xv = __expf(pv[k]) * uf;           // exp(0)*0 = 0 for !ld
            bool bit = (uw[k] >> cls) & 1;
            unsigned long long mk = __ballot(bit);
            if ((tid & 63) == 0) ybits[(tid >> 6) + (k << 2)] = mk;
            if (inr) sx[r * SS + c] = xv;
            c += 4; r += 6;
            if (c >= 42) { c -= 42; r += 1; }
        }
        if (tid == 0) { ybits[28] = 0ull; ybits[29] = 0ull; }
    }
    __syncthreads();

    // ---- horizontal conv: 42 rows x 6 strips of 6 outputs (252 threads)
    if (tid < 252) {
        int rr = tid / 6, s = tid - (tid / 6) * 6;
        int c0 = s * 6;
        const float* px = sx + rr * SS + c0;
        float ac0[6] = {}, ac1[6] = {}, ac2[6] = {}, ac3[6] = {};
        unsigned long long win;
        {
            int i0 = rr * 42 + c0;
            int w = i0 >> 6, sh = i0 & 63;
            unsigned long long lo = ybits[w], hi = ybits[w + 1];
            win = sh ? ((lo >> sh) | (hi << (64 - sh))) : lo;
        }
#pragma unroll
        for (int j = 0; j < 16; ++j) {
            float xv = px[j];
            float xx = xv * xv;
            bool bit = (win >> j) & 1;
            float yv = bit ? 1.f : 0.f;
            float xy = bit ? xv : 0.f;
#pragma unroll
            for (int o = 0; o < 6; ++o) {
                int kk = j - o;
                if (kk >= 0 && kk <= 10) {
                    float g = gk[kk];
                    ac0[o] = fmaf(g, xv, ac0[o]);
                    ac1[o] = fmaf(g, yv, ac1[o]);
                    ac2[o] = fmaf(g, xx, ac2[o]);
                    ac3[o] = fmaf(g, xy, ac3[o]);
                }
            }
        }
        int ob = rr * TS + c0;
#pragma unroll
        for (int o = 0; o < 6; ++o) {
            if (c0 + o < 32) {
                unsigned ua = __float_as_uint(ac0[o]);
                unsigned ub = __float_as_uint(ac1[o]);
                unsigned uc = __float_as_uint(ac2[o]);
                unsigned ud = __float_as_uint(ac3[o]);
                tm4[ob + o] = make_uint2((ua >> 16) | (ub & 0xFFFF0000u),
                                         (uc >> 16) | (ud & 0xFFFF0000u));
            }
        }
    }
    __syncthreads();

    // ---- vertical conv + SSIM (unpack bf16 pairs)
    const float C1 = 1e-4f, C2 = 9e-4f;
    const int cc = tid & 31, rg = tid >> 5, r0 = rg << 2;
    float a0[4] = {}, a1[4] = {}, a2[4] = {}, a3[4] = {};
    const int vb = r0 * TS + cc;
#pragma unroll
    for (int k = 0; k < 14; ++k) {
        uint2 tv2 = tm4[vb + k * TS];
        float m1v = __uint_as_float(tv2.x << 16);
        float m2v = __uint_as_float(tv2.x & 0xFFFF0000u);
        float xxv = __uint_as_float(tv2.y << 16);
        float xyv = __uint_as_float(tv2.y & 0xFFFF0000u);
#pragma unroll
        for (int j = 0; j < 4; ++j) {
            int kk = k - j;
            if (kk >= 0 && kk <= 10) {
                float g = gk[kk];
                a0[j] = fmaf(g, m1v, a0[j]);
                a1[j] = fmaf(g, m2v, a1[j]);
                a2[j] = fmaf(g, xxv, a2[j]);
                a3[j] = fmaf(g, xyv, a3[j]);
            }
        }
    }
    float cs_l = 0.f, ss_l = 0.f;
    const bool colok = (ox + cc < OW);
#pragma unroll
    for (int j = 0; j < 4; ++j) {
        if (colok && (oy + r0 + j < OH)) {
            float m1 = a0[j], m2 = a1[j];
            float sxx = a2[j], sxy_ = a3[j];
            float m11 = m1 * m1, m22 = m2 * m2, m12 = m1 * m2;
            float v1 = sxx - m11, v2 = m2 - m22, cov = sxy_ - m12;  // y^2=y
            float d1 = m11 + m22 + C1, d2 = v1 + v2 + C2;
            float n2 = 2.f * cov + C2;
            float q = 1.f / (d1 * d2);
            cs_l = fmaf(n2 * d1, q, cs_l);
            ss_l = fmaf((2.f * m12 + C1) * n2, q, ss_l);
        }
    }

    // ---- block reduction
    for (int off = 32; off; off >>= 1) {
        cs_l += __shfl_down(cs_l, off);
        ss_l += __shfl_down(ss_l, off);
    }
    int wv = tid >> 6, ln = tid & 63;
    if (ln == 0) { red[wv] = cs_l; red[4 + wv] = ss_l; }
    __syncthreads();
    if (tid == 0) {
        double cs_b = (double)red[0] + (double)red[1] + (double)red[2] + (double)red[3];
        double ss_b = (double)red[4] + (double)red[5] + (double)red[6] + (double)red[7];
        atomicAdd(&acc[bc], cs_b);
        atomicAdd(&acc[48 + bc], ss_b);
    }
}

// ---------------------------------------------------------------------------
// Scales 1-4 tile body (R11 arithmetic). tm4 stored immediately in the hconv
// phase (non-aliased); ONLY tm5 (aliasing sxy) waits for the extra barrier,
// so just ac4[6] crosses it — no spill pressure.
template <int PIN>
__device__ __forceinline__ void ssim_tile_g(
    const unsigned* __restrict__ XYs,
    int H, int W, int OH, int OW, int tilesX, int tile, int bc,
    double* __restrict__ acc, int scale,
    unsigned int* sxy, uint2* tm4, unsigned short* tm5, float* red) {
    constexpr int SS = 43;
    constexpr int TS = 35;
    const float gk[11] = GK_INIT;

    const int ty = tile / tilesX, tx = tile - ty * tilesX;
    const int oy = ty * 32, ox = tx * 32;
    const int tid = threadIdx.x;
    const bool interior = (oy + 41 < H) && (ox + 41 < W);

    constexpr int SC = 1 << PIN;
    const int SW = W * SC;
    const unsigned* Xb = XYs + (size_t)bc * H * W * SC * SC;

    // ---- halo load 42x42 (inline source pooling for PIN>0), packed store
    {
        int r = tid / 42, c = tid - (tid / 42) * 42;
#pragma unroll
        for (int k = 0; k < 7; ++k) {
            bool inr = (k < 6) || (tid < 228);
            int gy = oy + r, gx = ox + c;
            bool ld = inr && (interior || (gy < H && gx < W));
            unsigned wout = 0u;
            if (ld) {
                if constexpr (PIN == 0) {
                    wout = Xb[gy * SW + gx];            // already packed
                } else {
                    const unsigned* q = Xb + (SC * gy) * SW + SC * gx;
                    float s = 0.f; unsigned us = 0;
#pragma unroll
                    for (int a = 0; a < SC; ++a) {
                        const unsigned* qr = q + a * SW;
                        if constexpr (PIN == 1) {
                            uint2 w2 = *(const uint2*)qr;
                            s += __uint_as_float(w2.x << 16)
                               + __uint_as_float(w2.y << 16);
                            us += (w2.x >> 16) + (w2.y >> 16);
                        } else {
#pragma unroll
                            for (int e4 = 0; e4 < SC / 4; ++e4) {
                                uint4 w4 = *(const uint4*)(qr + e4 * 4);
                                s += (__uint_as_float(w4.x << 16)
                                    + __uint_as_float(w4.y << 16))
                                   + (__uint_as_float(w4.z << 16)
                                    + __uint_as_float(w4.w << 16));
                                us += ((w4.x >> 16) + (w4.y >> 16))
                                    + ((w4.z >> 16) + (w4.w >> 16));
                            }
                        }
                    }
                    float xv = s * (1.f / (float)(SC * SC));
                    unsigned yc = us >> (2 * PIN);
                    unsigned xb = (__float_as_uint(xv) + 0x8000u) >> 16;
                    wout = (yc << 16) | xb;
                }
            }
            if (inr) sxy[r * SS + c] = wout;
            c += 4; r += 6;
            if (c >= 42) { c -= 42; r += 1; }
        }
    }
    __syncthreads();

    // ---- horizontal conv (5 moments); tm4 stored immediately, ac4 kept
    float ac4[6] = {};
    int ob = 0, c0 = 0;
    if (tid < 252) {
        int rr = tid / 6, s = tid - (tid / 6) * 6;
        c0 = s * 6;
        const unsigned int* pxy = sxy + rr * SS + c0;
        float ac0[6] = {}, ac1[6] = {}, ac2[6] = {}, ac3[6] = {};
#pragma unroll
        for (int j = 0; j < 16; ++j) {
            unsigned v = pxy[j];
            float xv = __uint_as_float(v << 16);
            float yv = (float)(v >> 16);
            float xx = xv * xv;
            float xy = xv * yv;
            float yy = yv * yv;
#pragma unroll
            for (int o = 0; o < 6; ++o) {
                int kk = j - o;
                if (kk >= 0 && kk <= 10) {
                    float g = gk[kk];
                    ac0[o] = fmaf(g, xv, ac0[o]);
                    ac1[o] = fmaf(g, yv, ac1[o]);
                    ac2[o] = fmaf(g, xx, ac2[o]);
                    ac3[o] = fmaf(g, xy, ac3[o]);
                    ac4[o] = fmaf(g, yy, ac4[o]);
                }
            }
        }
        ob = rr * TS + c0;
#pragma unroll
        for (int o = 0; o < 6; ++o) {
            if (c0 + o < 32) {
                // bf16 round-to-nearest (half-up) pack; all moments >= 0.
                unsigned ua = __float_as_uint(ac0[o]) + 0x8000u;
                unsigned ub = __float_as_uint(ac1[o]) + 0x8000u;
                unsigned uc = __float_as_uint(ac2[o]) + 0x8000u;
                unsigned ud = __float_as_uint(ac3[o]) + 0x8000u;
                tm4[ob + o] = make_uint2((ua >> 16) | (ub & 0xFFFF0000u),
                                         (uc >> 16) | (ud & 0xFFFF0000u));
            }
        }
    }
    __syncthreads();                 // all sxy reads complete -> region reusable

    // ---- tm5 store (aliases sxy; only ac4 crossed the barrier)
    if (tid < 252) {
#pragma unroll
        for (int o = 0; o < 6; ++o) {
            if (c0 + o < 32) {
                unsigned ue = __float_as_uint(ac4[o]) + 0x8000u;
                tm5[ob + o] = (unsigned short)(ue >> 16);
            }
        }
    }
    __syncthreads();

    // ---- vertical conv + SSIM (unpack bf16)
    const float C1 = 1e-4f, C2 = 9e-4f;
    const int cc = tid & 31, rg = tid >> 5, r0 = rg << 2;
    float a0[4] = {}, a1[4] = {}, a2[4] = {}, a3[4] = {}, a4[4] = {};
    const int vb = r0 * TS + cc;
#pragma unroll
    for (int k = 0; k < 14; ++k) {
        uint2 tv = tm4[vb + k * TS];
        float t0 = __uint_as_float(tv.x << 16);
        float t1 = __uint_as_float(tv.x & 0xFFFF0000u);
        float t2 = __uint_as_float(tv.y << 16);
        float t3 = __uint_as_float(tv.y & 0xFFFF0000u);
        float t4 = __uint_as_float((unsigned)tm5[vb + k * TS] << 16);
#pragma unroll
        for (int j = 0; j < 4; ++j) {
            int kk = k - j;
            if (kk >= 0 && kk <= 10) {
                float g = gk[kk];
                a0[j] = fmaf(g, t0, a0[j]);
                a1[j] = fmaf(g, t1, a1[j]);
                a2[j] = fmaf(g, t2, a2[j]);
                a3[j] = fmaf(g, t3, a3[j]);
                a4[j] = fmaf(g, t4, a4[j]);
            }
        }
    }
    float cs_l = 0.f, ss_l = 0.f;
    const bool colok = (ox + cc < OW);
#pragma unroll
    for (int j = 0; j < 4; ++j) {
        if (colok && (oy + r0 + j < OH)) {
            float m1 = a0[j];
            float m2 = a1[j] * (1.f / 256.f);
            float sxx = a2[j];
            float sxy_ = a3[j] * (1.f / 256.f);
            float syy_ = a4[j] * (1.f / 65536.f);
            float m11 = m1 * m1, m22 = m2 * m2, m12 = m1 * m2;
            float v1 = sxx - m11, v2 = syy_ - m22, cov = sxy_ - m12;
            float d1 = m11 + m22 + C1, d2 = v1 + v2 + C2;
            float n2 = 2.f * cov + C2;
            float q = 1.f / (d1 * d2);
            cs_l = fmaf(n2 * d1, q, cs_l);
            ss_l = fmaf((2.f * m12 + C1) * n2, q, ss_l);
        }
    }

    // ---- block reduction
    for (int offs = 32; offs; offs >>= 1) {
        cs_l += __shfl_down(cs_l, offs);
        ss_l += __shfl_down(ss_l, offs);
    }
    int wv = tid >> 6, ln = tid & 63;
    if (ln == 0) { red[wv] = cs_l; red[4 + wv] = ss_l; }
    __syncthreads();
    if (tid == 0) {
        double cs_b = (double)red[0] + (double)red[1] + (double)red[2] + (double)red[3];
        double ss_b = (double)red[4] + (double)red[5] + (double)red[6] + (double)red[7];
        atomicAdd(&acc[scale * 96 + bc], cs_b);
        atomicAdd(&acc[scale * 96 + 48 + bc], ss_b);
    }
}

// ---------------------------------------------------------------------------
// MERGED dispatch (validated mapping): 16368 blocks = 12288 scale-0 +
// 4080 scales-1-4, interleaved; rest sub-order heavy-first. 8 blocks/CU.
__global__ __launch_bounds__(256, 8)
void k_main(const float* __restrict__ pred, const unsigned* __restrict__ UT,
            const unsigned* __restrict__ XY1, double* __restrict__ acc) {
    __shared__ SMem sm;
    const int gb = blockIdx.x;

    int s0_idx = -1, rest_idx = -1;
    if (gb < 16320) {
        int r = gb & 3, q = gb >> 2;
        if (r == 0) rest_idx = q;                 // 4080 rest blocks
        else        s0_idx = 3 * q + (r - 1);     // 12240 scale-0 blocks
    } else {
        s0_idx = 12240 + (gb - 16320);            // last 48 scale-0 blocks
    }

    if (s0_idx >= 0) {
        ssim0_tile(pred, UT, acc, s0_idx & 255, s0_idx >> 8,
                   sm.s0.sx, sm.s0.tm4, sm.s0.ybits, sm.s0.red);
        return;
    }
    const int gq = rest_idx;
    if (gq < 48) {                          // scale 4: 1 tile x 48 bc
        ssim_tile_g<3>(XY1, 32, 32, 22, 22, 1, 0, gq,
                       acc, 4, sm.rg.ovl.sxy, sm.rg.tm4, sm.rg.ovl.tm5, sm.rg.red);
    } else if (gq < 240) {                  // scale 3: 4 tiles x 48 bc
        int t = gq - 48;
        ssim_tile_g<2>(XY1, 64, 64, 54, 54, 2, t & 3, t >> 2,
                       acc, 3, sm.rg.ovl.sxy, sm.rg.tm4, sm.rg.ovl.tm5, sm.rg.red);
    } else if (gq < 1008) {                 // scale 2: 16 tiles x 48 bc
        int t = gq - 240;
        ssim_tile_g<1>(XY1, 128, 128, 118, 118, 4, t & 15, t >> 4,
                       acc, 2, sm.rg.ovl.sxy, sm.rg.tm4, sm.rg.ovl.tm5, sm.rg.red);
    } else {                                // scale 1: 64 tiles x 48 bc
        int t = gq - 1008;
        ssim_tile_g<0>(XY1, 256, 256, 246, 246, 8, t & 63, t >> 6,
                       acc, 1, sm.rg.ovl.sxy, sm.rg.tm4, sm.rg.ovl.tm5, sm.rg.red);
    }
}

// ---------------------------------------------------------------------------
__global__ void k_final(const double* __restrict__ acc, float* __restrict__ out) {
    const float wts[5] = {0.0448f, 0.2856f, 0.3001f, 0.2363f, 0.1333f};
    const float cnt[5] = {252004.f, 60516.f, 13924.f, 2916.f, 484.f}; // 502^2..22^2
    int tid = threadIdx.x;
    float msss = 0.f;
    if (tid < BC) {
        msss = 1.f;
#pragma unroll
        for (int s = 0; s < 5; ++s) {
            double a = (s < 4) ? acc[s * 96 + tid] : acc[s * 96 + 48 + tid];
            float v = fmaxf((float)(a / (double)cnt[s]), 0.f);
            msss *= powf(v, wts[s]);
        }
    }
    for (int off = 32; off; off >>= 1) msss += __shfl_down(msss, off);
    if (tid == 0) out[0] = 1.f - msss * (1.f / (float)BC);
}

// ---------------------------------------------------------------------------
extern "C" void kernel_launch(void* const* d_in, const int* in_sizes, int n_in,
                              void* d_out, int out_size, void* d_ws, size_t ws_size,
                              hipStream_t stream) {
    const float* pred = (const float*)d_in[0];
    const int*   tgt  = (const int*)d_in[1];
    float* out = (float*)d_out;

    // workspace layout — ~16 MB (22 MB proven safe)
    double* acc = (double*)d_ws;                       // 480 doubles
    unsigned* UT  = (unsigned*)(acc + 480);            // [4,512,512]   4 MB
    unsigned* XY1 = UT + (size_t)NB * HW0;             // [48,256,256] 12 MB

    k_prep<<<1024, 256, 0, stream>>>(pred, tgt, UT, XY1, acc);

    k_main<<<16368, 256, 0, stream>>>(pred, UT, XY1, acc);

    k_final<<<1, 64, 0, stream>>>(acc, out);
}

// Round 14
// 220.514 us; speedup vs baseline: 1.0820x; 1.0820x over previous
//
#include <hip/hip_runtime.h>

#define NCH 12
#define NB  4
#define BC  48
#define HW0 (512 * 512)

// Gaussian 1-D weights (win=11, sigma=1.5), exact to f32 — computed offline.
#define GK_INIT { 0.00102840f, 0.00759863f, 0.03600078f, 0.10936081f, \
                  0.21300541f, 0.26601164f, 0.21300541f, 0.10936081f, \
                  0.03600078f, 0.00759863f, 0.00102840f }

// ---------------------------------------------------------------------------
// Prep (single-pass, validated R11 form): one thread per 2x2 patch.
// UT = {u bf16 (hi16) | one-hot mask (lo16)}; XY1 = {y count<<16 | x bf16}.
__global__ __launch_bounds__(256)
void k_prep(const float* __restrict__ pred, const int* __restrict__ tgt,
            unsigned* __restrict__ UT, unsigned* __restrict__ XY1,
            double* __restrict__ acc) {
    if (blockIdx.x == 0) {
        for (int t = threadIdx.x; t < 480; t += 256) acc[t] = 0.0;
    }
    const int blk = blockIdx.x;          // 0..1023
    const int b  = blk >> 8;             // batch
    const int py = blk & 255;            // patch row
    const int px = threadIdx.x;          // patch col
    const size_t o00 = (size_t)(2 * py) * 512 + 2 * px;
    const size_t o10 = o00 + 512;
    const float* Pb = pred + (size_t)b * NCH * HW0;

    float ex[NCH], ey[NCH], ez[NCH], ew[NCH];
    float s00 = 0.f, s01 = 0.f, s10 = 0.f, s11 = 0.f;
#pragma unroll
    for (int c = 0; c < NCH; ++c) {
        const float* pc = Pb + (size_t)c * HW0;
        float2 r0 = *(const float2*)(pc + o00);
        float2 r1 = *(const float2*)(pc + o10);
        ex[c] = __expf(r0.x); ey[c] = __expf(r0.y);
        ez[c] = __expf(r1.x); ew[c] = __expf(r1.y);
        s00 += ex[c]; s01 += ey[c]; s10 += ez[c]; s11 += ew[c];
    }
    float u00 = 1.f / s00, u01 = 1.f / s01, u10 = 1.f / s10, u11 = 1.f / s11;

    const int* Tb = tgt + (size_t)b * HW0;
    int2 t0 = *(const int2*)(Tb + o00);
    int2 t1 = *(const int2*)(Tb + o10);

    unsigned* UTb = UT + (size_t)b * HW0;
    {
        unsigned w00 = (((__float_as_uint(u00) + 0x8000u) >> 16) << 16) | (1u << t0.x);
        unsigned w01 = (((__float_as_uint(u01) + 0x8000u) >> 16) << 16) | (1u << t0.y);
        unsigned w10 = (((__float_as_uint(u10) + 0x8000u) >> 16) << 16) | (1u << t1.x);
        unsigned w11 = (((__float_as_uint(u11) + 0x8000u) >> 16) << 16) | (1u << t1.y);
        *(uint2*)(UTb + o00) = make_uint2(w00, w01);
        *(uint2*)(UTb + o10) = make_uint2(w10, w11);
    }

#pragma unroll
    for (int c = 0; c < NCH; ++c) {
        float xs = 0.25f * (ex[c] * u00 + ey[c] * u01 + ez[c] * u10 + ew[c] * u11);
        unsigned xb = (__float_as_uint(xs) + 0x8000u) >> 16;   // bf16 rn
        unsigned cnt = (unsigned)(t0.x == c) + (unsigned)(t0.y == c)
                     + (unsigned)(t1.x == c) + (unsigned)(t1.y == c);
        size_t oidx = ((size_t)(b * NCH + c) * 256 + py) * 256 + px;
        XY1[oidx] = ((cnt << 6) << 16) | xb;                   // {y*256 | x bf16}
    }
}

// ---------------------------------------------------------------------------
// LDS union = 19.3 KB (R13 layout): s0 non-overlapped; rest aliases ONLY the
// small tm5 onto the dead sxy halo. 19.3 KB < 20 KB -> the HARDWARE can fit
// 8 blocks/CU. Register budget is decoupled: __launch_bounds__(256,7) keeps
// the R11 no-spill allocation (36 VGPR); 8 blocks x 4 waves x 36 VGPR =
// 288/SIMD <= 512, so the scheduler can still pack 8 blocks.
union SMem {
    struct {
        float sx[42 * 43 + 4];                  // 7240 B
        uint2 tm4[42 * 35];                     // 11760 B
        unsigned long long ybits[30];           // 240 B
        float red[8];                           // 32 B   => 19272 B
    } s0;
    struct {
        union {
            unsigned int sxy[42 * 43 + 4];      // halo (dead after hconv)
            unsigned short tm5[42 * 35];        // yy moment (written after)
        } ovl;                                  // 7240 B
        uint2 tm4[42 * 35];                     // 11760 B
        float red[8];                           // 32 B   => 19032 B
    } rg;
};

// ---------------------------------------------------------------------------
// Scale-0 SSIM tile — VERBATIM R11 body (2 barriers, no aliasing).
__device__ __forceinline__ void ssim0_tile(
    const float* __restrict__ pred, const unsigned* __restrict__ UT,
    double* __restrict__ acc, int tile, int bc,
    float* sx, uint2* tm4, unsigned long long* ybits, float* red) {
    constexpr int SS = 43;
    constexpr int TS = 35;
    constexpr int H = 512, W = 512, OH = 502, OW = 502, tilesX = 16;
    const float gk[11] = GK_INIT;

    const int ty = tile / tilesX, tx = tile - ty * tilesX;
    const int oy = ty * 32, ox = tx * 32;
    const int tid = threadIdx.x;
    const bool interior = (oy + 41 < H) && (ox + 41 < W);

    const int b = bc / NCH, cls = bc - (bc / NCH) * NCH;
    const float* Pb = pred + (((size_t)b * NCH + cls) << 18);
    const unsigned* Ub = UT + ((size_t)b << 18);

    // ---- halo 42x42, phase A: issue all loads (no cross-lane ops)
    float pv[7];
    unsigned uw[7];
    {
        int r = tid / 42, c = tid - (tid / 42) * 42;
#pragma unroll
        for (int k = 0; k < 7; ++k) {
            bool inr = (k < 6) || (tid < 228);
            int gy = oy + r, gx = ox + c;
            bool ld = inr && (interior || (gy < H && gx < W));
            pv[k] = 0.f; uw[k] = 0u;
            if (ld) {
                int off = gy * W + gx;
                pv[k] = Pb[off];
                uw[k] = Ub[off];
            }
            c += 4; r += 6;
            if (c >= 42) { c -= 42; r += 1; }
        }
    }
    // ---- halo phase B: exp + ballot + LDS store
    {
        int r = tid / 42, c = tid - (tid / 42) * 42;
#pragma unroll
        for (int k = 0; k < 7; ++k) {
            bool inr = (k < 6) || (tid < 228);
            float uf = __uint_as_float(uw[k] & 0xFFFF0000u);
            float xv = __expf(pv[k]) * uf;           // exp(0)*0 = 0 for !ld
            bool bit = (uw[k] >> cls) & 1;
            unsigned long long mk = __ballot(bit);
            if ((tid & 63) == 0) ybits[(tid >> 6) + (k << 2)] = mk;
            if (inr) sx[r * SS + c] = xv;
            c += 4; r += 6;
            if (c >= 42) { c -= 42; r += 1; }
        }
        if (tid == 0) { ybits[28] = 0ull; ybits[29] = 0ull; }
    }
    __syncthreads();

    // ---- horizontal conv: 42 rows x 6 strips of 6 outputs (252 threads)
    if (tid < 252) {
        int rr = tid / 6, s = tid - (tid / 6) * 6;
        int c0 = s * 6;
        const float* px = sx + rr * SS + c0;
        float ac0[6] = {}, ac1[6] = {}, ac2[6] = {}, ac3[6] = {};
        unsigned long long win;
        {
            int i0 = rr * 42 + c0;
            int w = i0 >> 6, sh = i0 & 63;
            unsigned long long lo = ybits[w], hi = ybits[w + 1];
            win = sh ? ((lo >> sh) | (hi << (64 - sh))) : lo;
        }
#pragma unroll
        for (int j = 0; j < 16; ++j) {
            float xv = px[j];
            float xx = xv * xv;
            bool bit = (win >> j) & 1;
            float yv = bit ? 1.f : 0.f;
            float xy = bit ? xv : 0.f;
#pragma unroll
            for (int o = 0; o < 6; ++o) {
                int kk = j - o;
                if (kk >= 0 && kk <= 10) {
                    float g = gk[kk];
                    ac0[o] = fmaf(g, xv, ac0[o]);
                    ac1[o] = fmaf(g, yv, ac1[o]);
                    ac2[o] = fmaf(g, xx, ac2[o]);
                    ac3[o] = fmaf(g, xy, ac3[o]);
                }
            }
        }
        int ob = rr * TS + c0;
#pragma unroll
        for (int o = 0; o < 6; ++o) {
            if (c0 + o < 32) {
                unsigned ua = __float_as_uint(ac0[o]);
                unsigned ub = __float_as_uint(ac1[o]);
                unsigned uc = __float_as_uint(ac2[o]);
                unsigned ud = __float_as_uint(ac3[o]);
                tm4[ob + o] = make_uint2((ua >> 16) | (ub & 0xFFFF0000u),
                                         (uc >> 16) | (ud & 0xFFFF0000u));
            }
        }
    }
    __syncthreads();

    // ---- vertical conv + SSIM (unpack bf16 pairs)
    const float C1 = 1e-4f, C2 = 9e-4f;
    const int cc = tid & 31, rg = tid >> 5, r0 = rg << 2;
    float a0[4] = {}, a1[4] = {}, a2[4] = {}, a3[4] = {};
    const int vb = r0 * TS + cc;
#pragma unroll
    for (int k = 0; k < 14; ++k) {
        uint2 tv2 = tm4[vb + k * TS];
        float m1v = __uint_as_float(tv2.x << 16);
        float m2v = __uint_as_float(tv2.x & 0xFFFF0000u);
        float xxv = __uint_as_float(tv2.y << 16);
        float xyv = __uint_as_float(tv2.y & 0xFFFF0000u);
#pragma unroll
        for (int j = 0; j < 4; ++j) {
            int kk = k - j;
            if (kk >= 0 && kk <= 10) {
                float g = gk[kk];
                a0[j] = fmaf(g, m1v, a0[j]);
                a1[j] = fmaf(g, m2v, a1[j]);
                a2[j] = fmaf(g, xxv, a2[j]);
                a3[j] = fmaf(g, xyv, a3[j]);
            }
        }
    }
    float cs_l = 0.f, ss_l = 0.f;
    const bool colok = (ox + cc < OW);
#pragma unroll
    for (int j = 0; j < 4; ++j) {
        if (colok && (oy + r0 + j < OH)) {
            float m1 = a0[j], m2 = a1[j];
            float sxx = a2[j], sxy_ = a3[j];
            float m11 = m1 * m1, m22 = m2 * m2, m12 = m1 * m2;
            float v1 = sxx - m11, v2 = m2 - m22, cov = sxy_ - m12;  // y^2=y
            float d1 = m11 + m22 + C1, d2 = v1 + v2 + C2;
            float n2 = 2.f * cov + C2;
            float q = 1.f / (d1 * d2);
            cs_l = fmaf(n2 * d1, q, cs_l);
            ss_l = fmaf((2.f * m12 + C1) * n2, q, ss_l);
        }
    }

    // ---- block reduction
    for (int off = 32; off; off >>= 1) {
        cs_l += __shfl_down(cs_l, off);
        ss_l += __shfl_down(ss_l, off);
    }
    int wv = tid >> 6, ln = tid & 63;
    if (ln == 0) { red[wv] = cs_l; red[4 + wv] = ss_l; }
    __syncthreads();
    if (tid == 0) {
        double cs_b = (double)red[0] + (double)red[1] + (double)red[2] + (double)red[3];
        double ss_b = (double)red[4] + (double)red[5] + (double)red[6] + (double)red[7];
        atomicAdd(&acc[bc], cs_b);
        atomicAdd(&acc[48 + bc], ss_b);
    }
}

// ---------------------------------------------------------------------------
// Scales 1-4 tile body (R13 structure): tm4 stored immediately in hconv
// (non-aliased); only tm5 (aliasing sxy) waits for the extra barrier, so
// just ac4[6] crosses it.
template <int PIN>
__device__ __forceinline__ void ssim_tile_g(
    const unsigned* __restrict__ XYs,
    int H, int W, int OH, int OW, int tilesX, int tile, int bc,
    double* __restrict__ acc, int scale,
    unsigned int* sxy, uint2* tm4, unsigned short* tm5, float* red) {
    constexpr int SS = 43;
    constexpr int TS = 35;
    const float gk[11] = GK_INIT;

    const int ty = tile / tilesX, tx = tile - ty * tilesX;
    const int oy = ty * 32, ox = tx * 32;
    const int tid = threadIdx.x;
    const bool interior = (oy + 41 < H) && (ox + 41 < W);

    constexpr int SC = 1 << PIN;
    const int SW = W * SC;
    const unsigned* Xb = XYs + (size_t)bc * H * W * SC * SC;

    // ---- halo load 42x42 (inline source pooling for PIN>0), packed store
    {
        int r = tid / 42, c = tid - (tid / 42) * 42;
#pragma unroll
        for (int k = 0; k < 7; ++k) {
            bool inr = (k < 6) || (tid < 228);
            int gy = oy + r, gx = ox + c;
            bool ld = inr && (interior || (gy < H && gx < W));
            unsigned wout = 0u;
            if (ld) {
                if constexpr (PIN == 0) {
                    wout = Xb[gy * SW + gx];            // already packed
                } else {
                    const unsigned* q = Xb + (SC * gy) * SW + SC * gx;
                    float s = 0.f; unsigned us = 0;
#pragma unroll
                    for (int a = 0; a < SC; ++a) {
                        const unsigned* qr = q + a * SW;
                        if constexpr (PIN == 1) {
                            uint2 w2 = *(const uint2*)qr;
                            s += __uint_as_float(w2.x << 16)
                               + __uint_as_float(w2.y << 16);
                            us += (w2.x >> 16) + (w2.y >> 16);
                        } else {
#pragma unroll
                            for (int e4 = 0; e4 < SC / 4; ++e4) {
                                uint4 w4 = *(const uint4*)(qr + e4 * 4);
                                s += (__uint_as_float(w4.x << 16)
                                    + __uint_as_float(w4.y << 16))
                                   + (__uint_as_float(w4.z << 16)
                                    + __uint_as_float(w4.w << 16));
                                us += ((w4.x >> 16) + (w4.y >> 16))
                                    + ((w4.z >> 16) + (w4.w >> 16));
                            }
                        }
                    }
                    float xv = s * (1.f / (float)(SC * SC));
                    unsigned yc = us >> (2 * PIN);
                    unsigned xb = (__float_as_uint(xv) + 0x8000u) >> 16;
                    wout = (yc << 16) | xb;
                }
            }
            if (inr) sxy[r * SS + c] = wout;
            c += 4; r += 6;
            if (c >= 42) { c -= 42; r += 1; }
        }
    }
    __syncthreads();

    // ---- horizontal conv (5 moments); tm4 stored immediately, ac4 kept
    float ac4[6] = {};
    int ob = 0, c0 = 0;
    if (tid < 252) {
        int rr = tid / 6, s = tid - (tid / 6) * 6;
        c0 = s * 6;
        const unsigned int* pxy = sxy + rr * SS + c0;
        float ac0[6] = {}, ac1[6] = {}, ac2[6] = {}, ac3[6] = {};
#pragma unroll
        for (int j = 0; j < 16; ++j) {
            unsigned v = pxy[j];
            float xv = __uint_as_float(v << 16);
            float yv = (float)(v >> 16);
            float xx = xv * xv;
            float xy = xv * yv;
            float yy = yv * yv;
#pragma unroll
            for (int o = 0; o < 6; ++o) {
                int kk = j - o;
                if (kk >= 0 && kk <= 10) {
                    float g = gk[kk];
                    ac0[o] = fmaf(g, xv, ac0[o]);
                    ac1[o] = fmaf(g, yv, ac1[o]);
                    ac2[o] = fmaf(g, xx, ac2[o]);
                    ac3[o] = fmaf(g, xy, ac3[o]);
                    ac4[o] = fmaf(g, yy, ac4[o]);
                }
            }
        }
        ob = rr * TS + c0;
#pragma unroll
        for (int o = 0; o < 6; ++o) {
            if (c0 + o < 32) {
                // bf16 round-to-nearest (half-up) pack; all moments >= 0.
                unsigned ua = __float_as_uint(ac0[o]) + 0x8000u;
                unsigned ub = __float_as_uint(ac1[o]) + 0x8000u;
                unsigned uc = __float_as_uint(ac2[o]) + 0x8000u;
                unsigned ud = __float_as_uint(ac3[o]) + 0x8000u;
                tm4[ob + o] = make_uint2((ua >> 16) | (ub & 0xFFFF0000u),
                                         (uc >> 16) | (ud & 0xFFFF0000u));
            }
        }
    }
    __syncthreads();                 // all sxy reads complete -> region reusable

    // ---- tm5 store (aliases sxy; only ac4 crossed the barrier)
    if (tid < 252) {
#pragma unroll
        for (int o = 0; o < 6; ++o) {
            if (c0 + o < 32) {
                unsigned ue = __float_as_uint(ac4[o]) + 0x8000u;
                tm5[ob + o] = (unsigned short)(ue >> 16);
            }
        }
    }
    __syncthreads();

    // ---- vertical conv + SSIM (unpack bf16)
    const float C1 = 1e-4f, C2 = 9e-4f;
    const int cc = tid & 31, rg = tid >> 5, r0 = rg << 2;
    float a0[4] = {}, a1[4] = {}, a2[4] = {}, a3[4] = {}, a4[4] = {};
    const int vb = r0 * TS + cc;
#pragma unroll
    for (int k = 0; k < 14; ++k) {
        uint2 tv = tm4[vb + k * TS];
        float t0 = __uint_as_float(tv.x << 16);
        float t1 = __uint_as_float(tv.x & 0xFFFF0000u);
        float t2 = __uint_as_float(tv.y << 16);
        float t3 = __uint_as_float(tv.y & 0xFFFF0000u);
        float t4 = __uint_as_float((unsigned)tm5[vb + k * TS] << 16);
#pragma unroll
        for (int j = 0; j < 4; ++j) {
            int kk = k - j;
            if (kk >= 0 && kk <= 10) {
                float g = gk[kk];
                a0[j] = fmaf(g, t0, a0[j]);
                a1[j] = fmaf(g, t1, a1[j]);
                a2[j] = fmaf(g, t2, a2[j]);
                a3[j] = fmaf(g, t3, a3[j]);
                a4[j] = fmaf(g, t4, a4[j]);
            }
        }
    }
    float cs_l = 0.f, ss_l = 0.f;
    const bool colok = (ox + cc < OW);
#pragma unroll
    for (int j = 0; j < 4; ++j) {
        if (colok && (oy + r0 + j < OH)) {
            float m1 = a0[j];
            float m2 = a1[j] * (1.f / 256.f);
            float sxx = a2[j];
            float sxy_ = a3[j] * (1.f / 256.f);
            float syy_ = a4[j] * (1.f / 65536.f);
            float m11 = m1 * m1, m22 = m2 * m2, m12 = m1 * m2;
            float v1 = sxx - m11, v2 = syy_ - m22, cov = sxy_ - m12;
            float d1 = m11 + m22 + C1, d2 = v1 + v2 + C2;
            float n2 = 2.f * cov + C2;
            float q = 1.f / (d1 * d2);
            cs_l = fmaf(n2 * d1, q, cs_l);
            ss_l = fmaf((2.f * m12 + C1) * n2, q, ss_l);
        }
    }

    // ---- block reduction
    for (int offs = 32; offs; offs >>= 1) {
        cs_l += __shfl_down(cs_l, offs);
        ss_l += __shfl_down(ss_l, offs);
    }
    int wv = tid >> 6, ln = tid & 63;
    if (ln == 0) { red[wv] = cs_l; red[4 + wv] = ss_l; }
    __syncthreads();
    if (tid == 0) {
        double cs_b = (double)red[0] + (double)red[1] + (double)red[2] + (double)red[3];
        double ss_b = (double)red[4] + (double)red[5] + (double)red[6] + (double)red[7];
        atomicAdd(&acc[scale * 96 + bc], cs_b);
        atomicAdd(&acc[scale * 96 + 48 + bc], ss_b);
    }
}

// ---------------------------------------------------------------------------
// MERGED dispatch (validated mapping): 16368 blocks = 12288 scale-0 +
// 4080 scales-1-4, interleaved; rest sub-order heavy-first.
// __launch_bounds__(256,7): R11's no-spill register allocation; hardware
// occupancy can still reach 8 blocks/CU because LDS = 19.3 KB < 20 KB.
__global__ __launch_bounds__(256, 7)
void k_main(const float* __restrict__ pred, const unsigned* __restrict__ UT,
            const unsigned* __restrict__ XY1, double* __restrict__ acc) {
    __shared__ SMem sm;
    const int gb = blockIdx.x;

    int s0_idx = -1, rest_idx = -1;
    if (gb < 16320) {
        int r = gb & 3, q = gb >> 2;
        if (r == 0) rest_idx = q;                 // 4080 rest blocks
        else        s0_idx = 3 * q + (r - 1);     // 12240 scale-0 blocks
    } else {
        s0_idx = 12240 + (gb - 16320);            // last 48 scale-0 blocks
    }

    if (s0_idx >= 0) {
        ssim0_tile(pred, UT, acc, s0_idx & 255, s0_idx >> 8,
                   sm.s0.sx, sm.s0.tm4, sm.s0.ybits, sm.s0.red);
        return;
    }
    const int gq = rest_idx;
    if (gq < 48) {                          // scale 4: 1 tile x 48 bc
        ssim_tile_g<3>(XY1, 32, 32, 22, 22, 1, 0, gq,
                       acc, 4, sm.rg.ovl.sxy, sm.rg.tm4, sm.rg.ovl.tm5, sm.rg.red);
    } else if (gq < 240) {                  // scale 3: 4 tiles x 48 bc
        int t = gq - 48;
        ssim_tile_g<2>(XY1, 64, 64, 54, 54, 2, t & 3, t >> 2,
                       acc, 3, sm.rg.ovl.sxy, sm.rg.tm4, sm.rg.ovl.tm5, sm.rg.red);
    } else if (gq < 1008) {                 // scale 2: 16 tiles x 48 bc
        int t = gq - 240;
        ssim_tile_g<1>(XY1, 128, 128, 118, 118, 4, t & 15, t >> 4,
                       acc, 2, sm.rg.ovl.sxy, sm.rg.tm4, sm.rg.ovl.tm5, sm.rg.red);
    } else {                                // scale 1: 64 tiles x 48 bc
        int t = gq - 1008;
        ssim_tile_g<0>(XY1, 256, 256, 246, 246, 8, t & 63, t >> 6,
                       acc, 1, sm.rg.ovl.sxy, sm.rg.tm4, sm.rg.ovl.tm5, sm.rg.red);
    }
}

// ---------------------------------------------------------------------------
__global__ void k_final(const double* __restrict__ acc, float* __restrict__ out) {
    const float wts[5] = {0.0448f, 0.2856f, 0.3001f, 0.2363f, 0.1333f};
    const float cnt[5] = {252004.f, 60516.f, 13924.f, 2916.f, 484.f}; // 502^2..22^2
    int tid = threadIdx.x;
    float msss = 0.f;
    if (tid < BC) {
        msss = 1.f;
#pragma unroll
        for (int s = 0; s < 5; ++s) {
            double a = (s < 4) ? acc[s * 96 + tid] : acc[s * 96 + 48 + tid];
            float v = fmaxf((float)(a / (double)cnt[s]), 0.f);
            msss *= powf(v, wts[s]);
        }
    }
    for (int off = 32; off; off >>= 1) msss += __shfl_down(msss, off);
    if (tid == 0) out[0] = 1.f - msss * (1.f / (float)BC);
}

// ---------------------------------------------------------------------------
extern "C" void kernel_launch(void* const* d_in, const int* in_sizes, int n_in,
                              void* d_out, int out_size, void* d_ws, size_t ws_size,
                              hipStream_t stream) {
    const float* pred = (const float*)d_in[0];
    const int*   tgt  = (const int*)d_in[1];
    float* out = (float*)d_out;

    // workspace layout — ~16 MB (22 MB proven safe)
    double* acc = (double*)d_ws;                       // 480 doubles
    unsigned* UT  = (unsigned*)(acc + 480);            // [4,512,512]   4 MB
    unsigned* XY1 = UT + (size_t)NB * HW0;             // [48,256,256] 12 MB

    k_prep<<<1024, 256, 0, stream>>>(pred, tgt, UT, XY1, acc);

    k_main<<<16368, 256, 0, stream>>>(pred, UT, XY1, acc);

    k_final<<<1, 64, 0, stream>>>(acc, out);
}

// Round 15
// 209.461 us; speedup vs baseline: 1.1391x; 1.0528x over previous
//
#include <hip/hip_runtime.h>

#define NCH 12
#define NB  4
#define BC  48
#define HW0 (512 * 512)

// Gaussian 1-D weights (win=11, sigma=1.5), exact to f32 — computed offline.
#define GK_INIT { 0.00102840f, 0.00759863f, 0.03600078f, 0.10936081f, \
                  0.21300541f, 0.26601164f, 0.21300541f, 0.10936081f, \
                  0.03600078f, 0.00759863f, 0.00102840f }

// ---------------------------------------------------------------------------
// Prep (single-pass, validated R11 form): one thread per 2x2 patch.
// UT = {u bf16 (hi16) | one-hot mask (lo16)}; XY1 = {y count<<16 | x bf16}.
__global__ __launch_bounds__(256)
void k_prep(const float* __restrict__ pred, const int* __restrict__ tgt,
            unsigned* __restrict__ UT, unsigned* __restrict__ XY1,
            double* __restrict__ acc) {
    if (blockIdx.x == 0) {
        for (int t = threadIdx.x; t < 480; t += 256) acc[t] = 0.0;
    }
    const int blk = blockIdx.x;          // 0..1023
    const int b  = blk >> 8;             // batch
    const int py = blk & 255;            // patch row
    const int px = threadIdx.x;          // patch col
    const size_t o00 = (size_t)(2 * py) * 512 + 2 * px;
    const size_t o10 = o00 + 512;
    const float* Pb = pred + (size_t)b * NCH * HW0;

    float ex[NCH], ey[NCH], ez[NCH], ew[NCH];
    float s00 = 0.f, s01 = 0.f, s10 = 0.f, s11 = 0.f;
#pragma unroll
    for (int c = 0; c < NCH; ++c) {
        const float* pc = Pb + (size_t)c * HW0;
        float2 r0 = *(const float2*)(pc + o00);
        float2 r1 = *(const float2*)(pc + o10);
        ex[c] = __expf(r0.x); ey[c] = __expf(r0.y);
        ez[c] = __expf(r1.x); ew[c] = __expf(r1.y);
        s00 += ex[c]; s01 += ey[c]; s10 += ez[c]; s11 += ew[c];
    }
    float u00 = 1.f / s00, u01 = 1.f / s01, u10 = 1.f / s10, u11 = 1.f / s11;

    const int* Tb = tgt + (size_t)b * HW0;
    int2 t0 = *(const int2*)(Tb + o00);
    int2 t1 = *(const int2*)(Tb + o10);

    unsigned* UTb = UT + (size_t)b * HW0;
    {
        unsigned w00 = (((__float_as_uint(u00) + 0x8000u) >> 16) << 16) | (1u << t0.x);
        unsigned w01 = (((__float_as_uint(u01) + 0x8000u) >> 16) << 16) | (1u << t0.y);
        unsigned w10 = (((__float_as_uint(u10) + 0x8000u) >> 16) << 16) | (1u << t1.x);
        unsigned w11 = (((__float_as_uint(u11) + 0x8000u) >> 16) << 16) | (1u << t1.y);
        *(uint2*)(UTb + o00) = make_uint2(w00, w01);
        *(uint2*)(UTb + o10) = make_uint2(w10, w11);
    }

#pragma unroll
    for (int c = 0; c < NCH; ++c) {
        float xs = 0.25f * (ex[c] * u00 + ey[c] * u01 + ez[c] * u10 + ew[c] * u11);
        unsigned xb = (__float_as_uint(xs) + 0x8000u) >> 16;   // bf16 rn
        unsigned cnt = (unsigned)(t0.x == c) + (unsigned)(t0.y == c)
                     + (unsigned)(t1.x == c) + (unsigned)(t1.y == c);
        size_t oidx = ((size_t)(b * NCH + c) * 256 + py) * 256 + px;
        XY1[oidx] = ((cnt << 6) << 16) | xb;                   // {y*256 | x bf16}
    }
}

// ---------------------------------------------------------------------------
// Shared-memory union (validated R11 layout): scale-0 branch 19.3 KB; rest
// branch 21.97 KB (packed {y u16 | x bf16} input) -> 7 blocks/CU static cap.
// NOTE (R12-R14 lesson): achieved occupancy is ~5 blocks/CU — below every
// static cap — so LDS-shaving/launch-bounds tuning does not help; forcing
// 8 waves/EU via __launch_bounds__(256,8) causes a 32-VGPR spill (77-159 MB
// scratch WRITE). Keep (256,7) and this layout.
union SMem {
    struct {
        float sx[42 * 43 + 4];
        uint2 tm4[42 * 35];
        unsigned long long ybits[30];
        float red[8];
    } s0;
    struct {
        unsigned int sxy[42 * 43 + 4];   // hi16: y count (0..256); lo16: x bf16
        uint2 tm4[42 * 35];
        unsigned short tm5[42 * 35];
        float red[8];
    } rg;
};

// ---------------------------------------------------------------------------
// Scale-0 SSIM tile (validated R11 body). Halo reads 2 streams (pred f32 +
// packed UT uint); phase A issues all 14 loads (MLP), phase B exp+ballot.
__device__ __forceinline__ void ssim0_tile(
    const float* __restrict__ pred, const unsigned* __restrict__ UT,
    double* __restrict__ acc, int tile, int bc,
    float* sx, uint2* tm4, unsigned long long* ybits, float* red) {
    constexpr int SS = 43;
    constexpr int TS = 35;
    constexpr int H = 512, W = 512, OH = 502, OW = 502, tilesX = 16;
    const float gk[11] = GK_INIT;

    const int ty = tile / tilesX, tx = tile - ty * tilesX;
    const int oy = ty * 32, ox = tx * 32;
    const int tid = threadIdx.x;
    const bool interior = (oy + 41 < H) && (ox + 41 < W);

    const int b = bc / NCH, cls = bc - (bc / NCH) * NCH;
    const float* Pb = pred + (((size_t)b * NCH + cls) << 18);
    const unsigned* Ub = UT + ((size_t)b << 18);

    // ---- halo 42x42, phase A: issue all loads (no cross-lane ops)
    float pv[7];
    unsigned uw[7];
    {
        int r = tid / 42, c = tid - (tid / 42) * 42;
#pragma unroll
        for (int k = 0; k < 7; ++k) {
            bool inr = (k < 6) || (tid < 228);
            int gy = oy + r, gx = ox + c;
            bool ld = inr && (interior || (gy < H && gx < W));
            pv[k] = 0.f; uw[k] = 0u;
            if (ld) {
                int off = gy * W + gx;
                pv[k] = Pb[off];
                uw[k] = Ub[off];
            }
            c += 4; r += 6;
            if (c >= 42) { c -= 42; r += 1; }
        }
    }
    // ---- halo phase B: exp + ballot + LDS store
    {
        int r = tid / 42, c = tid - (tid / 42) * 42;
#pragma unroll
        for (int k = 0; k < 7; ++k) {
            bool inr = (k < 6) || (tid < 228);
            float uf = __uint_as_float(uw[k] & 0xFFFF0000u);
            float xv = __expf(pv[k]) * uf;           // exp(0)*0 = 0 for !ld
            bool bit = (uw[k] >> cls) & 1;
            unsigned long long mk = __ballot(bit);
            if ((tid & 63) == 0) ybits[(tid >> 6) + (k << 2)] = mk;
            if (inr) sx[r * SS + c] = xv;
            c += 4; r += 6;
            if (c >= 42) { c -= 42; r += 1; }
        }
        if (tid == 0) { ybits[28] = 0ull; ybits[29] = 0ull; }
    }
    __syncthreads();

    // ---- horizontal conv: 42 rows x 6 strips of 6 outputs (252 threads)
    if (tid < 252) {
        int rr = tid / 6, s = tid - (tid / 6) * 6;
        int c0 = s * 6;
        const float* px = sx + rr * SS + c0;
        float ac0[6] = {}, ac1[6] = {}, ac2[6] = {}, ac3[6] = {};
        unsigned long long win;
        {
            int i0 = rr * 42 + c0;
            int w = i0 >> 6, sh = i0 & 63;
            unsigned long long lo = ybits[w], hi = ybits[w + 1];
            win = sh ? ((lo >> sh) | (hi << (64 - sh))) : lo;
        }
#pragma unroll
        for (int j = 0; j < 16; ++j) {
            float xv = px[j];
            float xx = xv * xv;
            bool bit = (win >> j) & 1;
            float yv = bit ? 1.f : 0.f;
            float xy = bit ? xv : 0.f;
#pragma unroll
            for (int o = 0; o < 6; ++o) {
                int kk = j - o;
                if (kk >= 0 && kk <= 10) {
                    float g = gk[kk];
                    ac0[o] = fmaf(g, xv, ac0[o]);
                    ac1[o] = fmaf(g, yv, ac1[o]);
                    ac2[o] = fmaf(g, xx, ac2[o]);
                    ac3[o] = fmaf(g, xy, ac3[o]);
                }
            }
        }
        int ob = rr * TS + c0;
#pragma unroll
        for (int o = 0; o < 6; ++o) {
            if (c0 + o < 32) {
                unsigned ua = __float_as_uint(ac0[o]);
                unsigned ub = __float_as_uint(ac1[o]);
                unsigned uc = __float_as_uint(ac2[o]);
                unsigned ud = __float_as_uint(ac3[o]);
                tm4[ob + o] = make_uint2((ua >> 16) | (ub & 0xFFFF0000u),
                                         (uc >> 16) | (ud & 0xFFFF0000u));
            }
        }
    }
    __syncthreads();

    // ---- vertical conv + SSIM (unpack bf16 pairs)
    const float C1 = 1e-4f, C2 = 9e-4f;
    const int cc = tid & 31, rg = tid >> 5, r0 = rg << 2;
    float a0[4] = {}, a1[4] = {}, a2[4] = {}, a3[4] = {};
    const int vb = r0 * TS + cc;
#pragma unroll
    for (int k = 0; k < 14; ++k) {
        uint2 tv2 = tm4[vb + k * TS];
        float m1v = __uint_as_float(tv2.x << 16);
        float m2v = __uint_as_float(tv2.x & 0xFFFF0000u);
        float xxv = __uint_as_float(tv2.y << 16);
        float xyv = __uint_as_float(tv2.y & 0xFFFF0000u);
#pragma unroll
        for (int j = 0; j < 4; ++j) {
            int kk = k - j;
            if (kk >= 0 && kk <= 10) {
                float g = gk[kk];
                a0[j] = fmaf(g, m1v, a0[j]);
                a1[j] = fmaf(g, m2v, a1[j]);
                a2[j] = fmaf(g, xxv, a2[j]);
                a3[j] = fmaf(g, xyv, a3[j]);
            }
        }
    }
    float cs_l = 0.f, ss_l = 0.f;
    const bool colok = (ox + cc < OW);
#pragma unroll
    for (int j = 0; j < 4; ++j) {
        if (colok && (oy + r0 + j < OH)) {
            float m1 = a0[j], m2 = a1[j];
            float sxx = a2[j], sxy_ = a3[j];
            float m11 = m1 * m1, m22 = m2 * m2, m12 = m1 * m2;
            float v1 = sxx - m11, v2 = m2 - m22, cov = sxy_ - m12;  // y^2=y
            float d1 = m11 + m22 + C1, d2 = v1 + v2 + C2;
            float n2 = 2.f * cov + C2;
            float q = 1.f / (d1 * d2);
            cs_l = fmaf(n2 * d1, q, cs_l);
            ss_l = fmaf((2.f * m12 + C1) * n2, q, ss_l);
        }
    }

    // ---- block reduction
    for (int off = 32; off; off >>= 1) {
        cs_l += __shfl_down(cs_l, off);
        ss_l += __shfl_down(ss_l, off);
    }
    int wv = tid >> 6, ln = tid & 63;
    if (ln == 0) { red[wv] = cs_l; red[4 + wv] = ss_l; }
    __syncthreads();
    if (tid == 0) {
        double cs_b = (double)red[0] + (double)red[1] + (double)red[2] + (double)red[3];
        double ss_b = (double)red[4] + (double)red[5] + (double)red[6] + (double)red[7];
        atomicAdd(&acc[bc], cs_b);
        atomicAdd(&acc[48 + bc], ss_b);
    }
}

// ---------------------------------------------------------------------------
// Scales 1-4 tile body (validated R11 form). Source is the packed XY1 stream
// (one uint/pixel): PIN=0 loads with ZERO repack; PIN>0 pools and repacks.
template <int PIN>
__device__ __forceinline__ void ssim_tile_g(
    const unsigned* __restrict__ XYs,
    int H, int W, int OH, int OW, int tilesX, int tile, int bc,
    double* __restrict__ acc, int scale,
    unsigned int* sxy, uint2* tm4, unsigned short* tm5, float* red) {
    constexpr int SS = 43;
    constexpr int TS = 35;
    const float gk[11] = GK_INIT;

    const int ty = tile / tilesX, tx = tile - ty * tilesX;
    const int oy = ty * 32, ox = tx * 32;
    const int tid = threadIdx.x;
    const bool interior = (oy + 41 < H) && (ox + 41 < W);

    constexpr int SC = 1 << PIN;
    const int SW = W * SC;
    const unsigned* Xb = XYs + (size_t)bc * H * W * SC * SC;

    // ---- halo load 42x42 (inline source pooling for PIN>0), packed store
    {
        int r = tid / 42, c = tid - (tid / 42) * 42;
#pragma unroll
        for (int k = 0; k < 7; ++k) {
            bool inr = (k < 6) || (tid < 228);
            int gy = oy + r, gx = ox + c;
            bool ld = inr && (interior || (gy < H && gx < W));
            unsigned wout = 0u;
            if (ld) {
                if constexpr (PIN == 0) {
                    wout = Xb[gy * SW + gx];            // already packed
                } else {
                    const unsigned* q = Xb + (SC * gy) * SW + SC * gx;
                    float s = 0.f; unsigned us = 0;
#pragma unroll
                    for (int a = 0; a < SC; ++a) {
                        const unsigned* qr = q + a * SW;
                        if constexpr (PIN == 1) {
                            uint2 w2 = *(const uint2*)qr;
                            s += __uint_as_float(w2.x << 16)
                               + __uint_as_float(w2.y << 16);
                            us += (w2.x >> 16) + (w2.y >> 16);
                        } else {
#pragma unroll
                            for (int e4 = 0; e4 < SC / 4; ++e4) {
                                uint4 w4 = *(const uint4*)(qr + e4 * 4);
                                s += (__uint_as_float(w4.x << 16)
                                    + __uint_as_float(w4.y << 16))
                                   + (__uint_as_float(w4.z << 16)
                                    + __uint_as_float(w4.w << 16));
                                us += ((w4.x >> 16) + (w4.y >> 16))
                                    + ((w4.z >> 16) + (w4.w >> 16));
                            }
                        }
                    }
                    float xv = s * (1.f / (float)(SC * SC));
                    unsigned yc = us >> (2 * PIN);
                    unsigned xb = (__float_as_uint(xv) + 0x8000u) >> 16;
                    wout = (yc << 16) | xb;
                }
            }
            if (inr) sxy[r * SS + c] = wout;
            c += 4; r += 6;
            if (c >= 42) { c -= 42; r += 1; }
        }
    }
    __syncthreads();

    // ---- horizontal conv (5 moments) from packed input
    if (tid < 252) {
        int rr = tid / 6, s = tid - (tid / 6) * 6;
        int c0 = s * 6;
        const unsigned int* pxy = sxy + rr * SS + c0;
        float ac0[6] = {}, ac1[6] = {}, ac2[6] = {}, ac3[6] = {}, ac4[6] = {};
#pragma unroll
        for (int j = 0; j < 16; ++j) {
            unsigned v = pxy[j];
            float xv = __uint_as_float(v << 16);
            float yv = (float)(v >> 16);
            float xx = xv * xv;
            float xy = xv * yv;
            float yy = yv * yv;
#pragma unroll
            for (int o = 0; o < 6; ++o) {
                int kk = j - o;
                if (kk >= 0 && kk <= 10) {
                    float g = gk[kk];
                    ac0[o] = fmaf(g, xv, ac0[o]);
                    ac1[o] = fmaf(g, yv, ac1[o]);
                    ac2[o] = fmaf(g, xx, ac2[o]);
                    ac3[o] = fmaf(g, xy, ac3[o]);
                    ac4[o] = fmaf(g, yy, ac4[o]);
                }
            }
        }
        int ob = rr * TS + c0;
#pragma unroll
        for (int o = 0; o < 6; ++o) {
            if (c0 + o < 32) {
                // bf16 round-to-nearest (half-up) pack; all moments >= 0.
                unsigned ua = __float_as_uint(ac0[o]) + 0x8000u;
                unsigned ub = __float_as_uint(ac1[o]) + 0x8000u;
                unsigned uc = __float_as_uint(ac2[o]) + 0x8000u;
                unsigned ud = __float_as_uint(ac3[o]) + 0x8000u;
                unsigned ue = __float_as_uint(ac4[o]) + 0x8000u;
                tm4[ob + o] = make_uint2((ua >> 16) | (ub & 0xFFFF0000u),
                                         (uc >> 16) | (ud & 0xFFFF0000u));
                tm5[ob + o] = (unsigned short)(ue >> 16);
            }
        }
    }
    __syncthreads();

    // ---- vertical conv + SSIM (unpack bf16)
    const float C1 = 1e-4f, C2 = 9e-4f;
    const int cc = tid & 31, rg = tid >> 5, r0 = rg << 2;
    float a0[4] = {}, a1[4] = {}, a2[4] = {}, a3[4] = {}, a4[4] = {};
    const int vb = r0 * TS + cc;
#pragma unroll
    for (int k = 0; k < 14; ++k) {
        uint2 tv = tm4[vb + k * TS];
        float t0 = __uint_as_float(tv.x << 16);
        float t1 = __uint_as_float(tv.x & 0xFFFF0000u);
        float t2 = __uint_as_float(tv.y << 16);
        float t3 = __uint_as_float(tv.y & 0xFFFF0000u);
        float t4 = __uint_as_float((unsigned)tm5[vb + k * TS] << 16);
#pragma unroll
        for (int j = 0; j < 4; ++j) {
            int kk = k - j;
            if (kk >= 0 && kk <= 10) {
                float g = gk[kk];
                a0[j] = fmaf(g, t0, a0[j]);
                a1[j] = fmaf(g, t1, a1[j]);
                a2[j] = fmaf(g, t2, a2[j]);
                a3[j] = fmaf(g, t3, a3[j]);
                a4[j] = fmaf(g, t4, a4[j]);
            }
        }
    }
    float cs_l = 0.f, ss_l = 0.f;
    const bool colok = (ox + cc < OW);
#pragma unroll
    for (int j = 0; j < 4; ++j) {
        if (colok && (oy + r0 + j < OH)) {
            float m1 = a0[j];
            float m2 = a1[j] * (1.f / 256.f);
            float sxx = a2[j];
            float sxy_ = a3[j] * (1.f / 256.f);
            float syy_ = a4[j] * (1.f / 65536.f);
            float m11 = m1 * m1, m22 = m2 * m2, m12 = m1 * m2;
            float v1 = sxx - m11, v2 = syy_ - m22, cov = sxy_ - m12;
            float d1 = m11 + m22 + C1, d2 = v1 + v2 + C2;
            float n2 = 2.f * cov + C2;
            float q = 1.f / (d1 * d2);
            cs_l = fmaf(n2 * d1, q, cs_l);
            ss_l = fmaf((2.f * m12 + C1) * n2, q, ss_l);
        }
    }

    // ---- block reduction
    for (int offs = 32; offs; offs >>= 1) {
        cs_l += __shfl_down(cs_l, offs);
        ss_l += __shfl_down(ss_l, offs);
    }
    int wv = tid >> 6, ln = tid & 63;
    if (ln == 0) { red[wv] = cs_l; red[4 + wv] = ss_l; }
    __syncthreads();
    if (tid == 0) {
        double cs_b = (double)red[0] + (double)red[1] + (double)red[2] + (double)red[3];
        double ss_b = (double)red[4] + (double)red[5] + (double)red[6] + (double)red[7];
        atomicAdd(&acc[scale * 96 + bc], cs_b);
        atomicAdd(&acc[scale * 96 + 48 + bc], ss_b);
    }
}

// ---------------------------------------------------------------------------
// MERGED dispatch (validated R6/R10/R11 mapping): 16368 blocks = 12288
// scale-0 + 4080 scales-1-4, interleaved; rest sub-order heavy-first.
__global__ __launch_bounds__(256, 7)
void k_main(const float* __restrict__ pred, const unsigned* __restrict__ UT,
            const unsigned* __restrict__ XY1, double* __restrict__ acc) {
    __shared__ SMem sm;
    const int gb = blockIdx.x;

    int s0_idx = -1, rest_idx = -1;
    if (gb < 16320) {
        int r = gb & 3, q = gb >> 2;
        if (r == 0) rest_idx = q;                 // 4080 rest blocks
        else        s0_idx = 3 * q + (r - 1);     // 12240 scale-0 blocks
    } else {
        s0_idx = 12240 + (gb - 16320);            // last 48 scale-0 blocks
    }

    if (s0_idx >= 0) {
        ssim0_tile(pred, UT, acc, s0_idx & 255, s0_idx >> 8,
                   sm.s0.sx, sm.s0.tm4, sm.s0.ybits, sm.s0.red);
        return;
    }
    const int gq = rest_idx;
    if (gq < 48) {                          // scale 4: 1 tile x 48 bc
        ssim_tile_g<3>(XY1, 32, 32, 22, 22, 1, 0, gq,
                       acc, 4, sm.rg.sxy, sm.rg.tm4, sm.rg.tm5, sm.rg.red);
    } else if (gq < 240) {                  // scale 3: 4 tiles x 48 bc
        int t = gq - 48;
        ssim_tile_g<2>(XY1, 64, 64, 54, 54, 2, t & 3, t >> 2,
                       acc, 3, sm.rg.sxy, sm.rg.tm4, sm.rg.tm5, sm.rg.red);
    } else if (gq < 1008) {                 // scale 2: 16 tiles x 48 bc
        int t = gq - 240;
        ssim_tile_g<1>(XY1, 128, 128, 118, 118, 4, t & 15, t >> 4,
                       acc, 2, sm.rg.sxy, sm.rg.tm4, sm.rg.tm5, sm.rg.red);
    } else {                                // scale 1: 64 tiles x 48 bc
        int t = gq - 1008;
        ssim_tile_g<0>(XY1, 256, 256, 246, 246, 8, t & 63, t >> 6,
                       acc, 1, sm.rg.sxy, sm.rg.tm4, sm.rg.tm5, sm.rg.red);
    }
}

// ---------------------------------------------------------------------------
__global__ void k_final(const double* __restrict__ acc, float* __restrict__ out) {
    const float wts[5] = {0.0448f, 0.2856f, 0.3001f, 0.2363f, 0.1333f};
    const float cnt[5] = {252004.f, 60516.f, 13924.f, 2916.f, 484.f}; // 502^2..22^2
    int tid = threadIdx.x;
    float msss = 0.f;
    if (tid < BC) {
        msss = 1.f;
#pragma unroll
        for (int s = 0; s < 5; ++s) {
            double a = (s < 4) ? acc[s * 96 + tid] : acc[s * 96 + 48 + tid];
            float v = fmaxf((float)(a / (double)cnt[s]), 0.f);
            msss *= powf(v, wts[s]);
        }
    }
    for (int off = 32; off; off >>= 1) msss += __shfl_down(msss, off);
    if (tid == 0) out[0] = 1.f - msss * (1.f / (float)BC);
}

// ---------------------------------------------------------------------------
extern "C" void kernel_launch(void* const* d_in, const int* in_sizes, int n_in,
                              void* d_out, int out_size, void* d_ws, size_t ws_size,
                              hipStream_t stream) {
    const float* pred = (const float*)d_in[0];
    const int*   tgt  = (const int*)d_in[1];
    float* out = (float*)d_out;

    // workspace layout — ~16 MB (22 MB proven safe)
    double* acc = (double*)d_ws;                       // 480 doubles
    unsigned* UT  = (unsigned*)(acc + 480);            // [4,512,512]   4 MB
    unsigned* XY1 = UT + (size_t)NB * HW0;             // [48,256,256] 12 MB

    k_prep<<<1024, 256, 0, stream>>>(pred, tgt, UT, XY1, acc);

    k_main<<<16368, 256, 0, stream>>>(pred, UT, XY1, acc);

    k_final<<<1, 64, 0, stream>>>(acc, out);
}